// Round 10
// baseline (125.808 us; speedup 1.0000x reference)
//
#include <hip/hip_runtime.h>

// GraphConvBlock, v10 = v8 inner math with 2-blocks/CU node stages.
// Node: block = 64oc x 2rows x 64pix, 256thr (4 waves = 2wr x 2kh), acts staged
// per K-HALF (33.8KB) + half-K weight chunks (8KB x 3-deep) -> 57KB LDS ->
// 2 blocks/CU, grid 512 all-resident. 18 phases (khalf,tap); half-1 acts
// reg-loaded in phase 8, committed between double barriers at phase 9.
// Stem + setup = v8 (stem repack/chunks unchanged; node chunks (och,khalf,tap)).

typedef __bf16 bf16x8 __attribute__((ext_vector_type(8)));
typedef float f32x4 __attribute__((ext_vector_type(4)));

union U4 { uint4 u; bf16x8 b; };

__device__ inline unsigned pk_bf16(float lo, float hi) {
  unsigned r;
  asm volatile("v_cvt_pk_bf16_f32 %0, %1, %2" : "=v"(r) : "v"(lo), "v"(hi));
  return r;
}

__device__ inline unsigned addpk(unsigned a, unsigned b) {
  float alo = __builtin_bit_cast(float, a << 16);
  float ahi = __builtin_bit_cast(float, a & 0xFFFF0000u);
  float blo = __builtin_bit_cast(float, b << 16);
  float bhi = __builtin_bit_cast(float, b & 0xFFFF0000u);
  return pk_bf16(alo + blo, ahi + bhi);
}

__device__ inline uint4 addpk4(uint4 a, uint4 b) {
  return make_uint4(addpk(a.x, b.x), addpk(a.y, b.y), addpk(a.z, b.z), addpk(a.w, b.w));
}

__device__ __forceinline__ void gload16(const unsigned* g, unsigned* l) {
  __builtin_amdgcn_global_load_lds(
      (const __attribute__((address_space(1))) unsigned*)(g),
      (__attribute__((address_space(3))) unsigned*)(l), 16, 0, 0);
}

template <int N>
__device__ __forceinline__ void waitcnt_vm_lgkm() {
  if constexpr (N == 0)
    asm volatile("s_waitcnt vmcnt(0) lgkmcnt(0)" ::: "memory");
  else if constexpr (N == 1)
    asm volatile("s_waitcnt vmcnt(1) lgkmcnt(0)" ::: "memory");
  else
    asm volatile("s_waitcnt vmcnt(2) lgkmcnt(0)" ::: "memory");
}

__device__ __forceinline__ void seal_lgkm_barrier() {
  asm volatile("s_waitcnt lgkmcnt(0)" ::: "memory");
  __builtin_amdgcn_s_barrier();
  __builtin_amdgcn_sched_barrier(0);
}

#define WB_WORDS 479232

// ---------------- fused setup kernel -----------------------------------------
// stem chunks: (ochalf*9+tap) of [64r][32j] (unchanged).
// node chunks: within stage, c2 = och*18 + khalf*9 + tap, each [64r][32j],
//   Wb word = 36864 + s*73728 + c2*2048 + r*32 + j, holding
//   w(oc=och*64+r, icpair = khalf*32 + (j^((r&7)<<2)), tap).
__global__ __launch_bounds__(512) void setup_all(
    const float* __restrict__ x, const float* __restrict__ W0,
    const float* __restrict__ Wn, unsigned* __restrict__ B0,
    unsigned* __restrict__ B1, unsigned* __restrict__ B2,
    unsigned* __restrict__ T, unsigned* __restrict__ Wb) {
  __shared__ float xl[2 * 64 * 65];
  const int tid = threadIdx.x;
  const int bid = blockIdx.x;
  const int n = bid & 7;

#pragma unroll
  for (int it = 0; it < 4; ++it) {
    unsigned gid = (unsigned)bid * 512 + tid + it * 131072u;
    if (gid < WB_WORDS) {
      unsigned val;
      if (gid < 36864) {
        int c = gid >> 11; int w = gid & 2047; int r = w >> 5; int j = w & 31;
        int ochalf = c / 9, tap = c % 9;
        int dy = tap / 3, dx = tap % 3;
        int icpair = j ^ ((r & 7) << 2);
        int oc = ochalf * 64 + r;
        size_t base = (((size_t)oc * 64 + 2 * icpair) * 3 + dy) * 3 + dx;
        val = pk_bf16(W0[base], W0[base + 9]);
      } else {
        unsigned g2 = gid - 36864;
        int s = g2 / 73728; unsigned r2 = g2 % 73728;
        const float* src = Wn + (size_t)s * 147456;
        int c2 = r2 >> 11; int w = r2 & 2047; int r = w >> 5; int j = w & 31;
        int och = c2 / 18; int rest = c2 % 18;
        int khalf = rest / 9, tap = rest % 9;
        int dy = tap / 3, dx = tap % 3;
        int icp = khalf * 32 + (j ^ ((r & 7) << 2));
        int oc = och * 64 + r;
        size_t base = (((size_t)oc * 128 + 2 * icp) * 3 + dy) * 3 + dx;
        val = pk_bf16(src[base], src[base + 9]);
      }
      Wb[gid] = val;
    }
  }

  {
    unsigned gid = (unsigned)bid * 512 + tid;
    if (gid < 116480) {
      unsigned* buf; int CW; unsigned u;
      if (gid < 99840) {
        buf = gid < 33280 ? B0 : (gid < 66560 ? B1 : B2);
        u = gid % 33280; CW = 64;
      } else {
        buf = T; u = gid - 99840; CW = 32;
      }
      int per_n = 65 * CW;
      int nn = u / per_n;
      unsigned v = u % per_n;
      int pix = (v * 4) / CW, cw = (v * 4) % CW;
      int row, col;
      if (pix < 66) { row = 0; col = pix; }
      else if (pix < 132) { row = 65; col = pix - 66; }
      else if (pix < 196) { row = pix - 131; col = 0; }
      else { row = pix - 195; col = 65; }
      *(uint4*)&buf[((((size_t)nn * 66 + row) * 66 + col) * CW) + cw] =
          make_uint4(0, 0, 0, 0);
    }
  }

  {
    int hh = bid >> 3;
    int sub = tid >> 8;
    int t8 = tid & 255;
    int h = hh * 2 + sub;
#pragma unroll
    for (int k = 0; k < 16; ++k) {
      int idx = t8 + k * 256;
      int ic = idx >> 6, w = idx & 63;
      xl[(sub * 64 + w) * 65 + ic] = x[(((size_t)n * 64 + ic) * 64 + h) * 64 + w];
    }
    __syncthreads();
#pragma unroll
    for (int k = 0; k < 8; ++k) {
      int idx = t8 + k * 256;
      int w = idx >> 5, icp = idx & 31;
      unsigned v = pk_bf16(xl[(sub * 64 + w) * 65 + icp * 2],
                           xl[(sub * 64 + w) * 65 + icp * 2 + 1]);
      int wp = w + 1;
      int pos = icp ^ ((wp & 7) << 2);
      T[(((size_t)n * 66 + (h + 1)) * 66 + wp) * 32 + pos] = v;
    }
  }
}

// ---------------- stem conv (v8 structure, CIN=64, grid 256 x 512) ------------
__global__ __launch_bounds__(512, 2) void conv_stem(
    const unsigned* __restrict__ in0, const unsigned* __restrict__ wb,
    const float* __restrict__ bias, unsigned* __restrict__ outp) {
  constexpr int WPP = 32, CHW = 2048, WL = 1, ROWW = 66 * 32;
  constexpr int ALDS_W = 16384;
  constexpr int R4_U4 = 4 * ROWW / 4, R2_U4 = 2 * ROWW / 4;
  constexpr int AJ4 = (R4_U4 + 511) / 512, LJ = (R2_U4 + 511) / 512;

  __shared__ unsigned Alds[ALDS_W];
  __shared__ unsigned Wlds[3][CHW];

  const int tid = threadIdx.x;
  const int lane = tid & 63;
  const int wav = tid >> 6;
  const int wr = wav >> 1;
  const int kh = wav & 1;
  const int l15 = lane & 15, q = lane >> 4;
  const int bid = blockIdx.x;
  const int n = bid & 7;
  const int ochalf = (bid >> 3) & 1;
  const int h0 = (bid >> 4) * 4;

  const unsigned* wbase = wb + (size_t)ochalf * 9 * CHW;
  const size_t abase = ((size_t)n * 66 + h0) * ROWW;
  const uint4* g0 = (const uint4*)(in0 + abase);

  uint4 l0[LJ];
#pragma unroll
  for (int j = 0; j < LJ; ++j) {
    int i = tid + j * 512;
    if (i < R2_U4) l0[j] = g0[R4_U4 + i];
  }
#pragma unroll
  for (int j = 0; j < AJ4; ++j) {
    int i = tid + j * 512;
    if (i < R4_U4) *(uint4*)&Alds[4 * i] = g0[i];
  }
#pragma unroll
  for (int s = 0; s < WL; ++s)
    gload16(wbase + s * 2048 + tid * 4, &Wlds[0][s * 2048 + wav * 256]);
#pragma unroll
  for (int s = 0; s < WL; ++s)
    gload16(wbase + CHW + s * 2048 + tid * 4, &Wlds[1][s * 2048 + wav * 256]);
  seal_lgkm_barrier();

  f32x4 acc[4][4];
#pragma unroll
  for (int m = 0; m < 4; ++m)
#pragma unroll
    for (int p = 0; p < 4; ++p) acc[m][p] = (f32x4)0.f;

#pragma unroll
  for (int t = 0; t < 9; ++t) {
    if (t < 8) waitcnt_vm_lgkm<WL>();
    else waitcnt_vm_lgkm<0>();
    __builtin_amdgcn_s_barrier();
    __builtin_amdgcn_sched_barrier(0);

    const unsigned* WB = Wlds[t % 3];
    const int dy = t / 3, dx = t % 3;
    const int arow = (wr + dy) * 66;
    const int kc = kh;

    __builtin_amdgcn_s_setprio(1);
    bf16x8 a[4];
#pragma unroll
    for (int m = 0; m < 4; ++m) {
      int r = m * 16 + l15;
      U4 u;
      u.u = *(const uint4*)&WB[r * WPP + ((kc * 16 + q * 4) ^ ((r & 7) << 2))];
      a[m] = u.b;
    }
#pragma unroll
    for (int p = 0; p < 4; ++p) {
      int col = p * 16 + l15 + dx;
      U4 u;
      u.u = *(const uint4*)&Alds[(arow + col) * WPP +
                                 ((kc * 16 + q * 4) ^ ((col & 7) << 2))];
      bf16x8 b = u.b;
#pragma unroll
      for (int m = 0; m < 4; ++m)
        acc[m][p] = __builtin_amdgcn_mfma_f32_16x16x32_bf16(a[m], b, acc[m][p], 0, 0, 0);
    }
    __builtin_amdgcn_s_setprio(0);
    __builtin_amdgcn_sched_barrier(0);

    if (t == 0) {
#pragma unroll
      for (int j = 0; j < LJ; ++j) {
        int i = tid + j * 512;
        if (i < R2_U4) *(uint4*)&Alds[4 * (R4_U4 + i)] = l0[j];
      }
    }
    if (t + 2 < 9) {
#pragma unroll
      for (int s = 0; s < WL; ++s)
        gload16(wbase + (size_t)(t + 2) * CHW + s * 2048 + tid * 4,
                &Wlds[(t + 2) % 3][s * 2048 + wav * 256]);
    }
    __builtin_amdgcn_sched_barrier(0);
  }

  __syncthreads();
  float* R = (float*)Alds;
  if (kh) {
#pragma unroll
    for (int m = 0; m < 4; ++m)
#pragma unroll
      for (int p = 0; p < 4; ++p)
        *(f32x4*)&R[(wr * 16 + m * 4 + p) * 256 + lane * 4] = acc[m][p];
  }
  __syncthreads();
  if (kh) return;
#pragma unroll
  for (int m = 0; m < 4; ++m)
#pragma unroll
    for (int p = 0; p < 4; ++p)
      acc[m][p] += *(const f32x4*)&R[(wr * 16 + m * 4 + p) * 256 + lane * 4];

  const int obase = ochalf * 64;
#pragma unroll
  for (int m = 0; m < 4; ++m) {
    int oc0 = obase + m * 16 + q * 4;
    float4 bb = *(const float4*)&bias[oc0];
    int icp0 = oc0 >> 1;
#pragma unroll
    for (int p = 0; p < 4; ++p) {
      int w = p * 16 + l15;
      int wp = w + 1;
      unsigned lo = pk_bf16(acc[m][p][0] + bb.x, acc[m][p][1] + bb.y);
      unsigned hi = pk_bf16(acc[m][p][2] + bb.z, acc[m][p][3] + bb.w);
      int pos = icp0 ^ ((wp & 7) << 2);
      size_t base = (((size_t)n * 66 + (h0 + 1 + wr)) * 66 + wp) * 64;
      *(uint2*)&outp[base + pos] = make_uint2(lo, hi);
    }
  }
}

// ---------------- node conv (CIN=128): 2-blocks/CU K-half schedule ------------
// 256 thr = 4 waves = 2wr x 2kh; wave = 64oc x 64pix (row h0+wr) x K-quarter.
// grid 512 = 2 ochalf x 8 n x 32 hp (h0 = hp*2). 18 phases: t = khalf*9 + tap.
template <bool DUAL, bool OUTF32>
__global__ __launch_bounds__(256, 2) void conv_node(
    const unsigned* __restrict__ in0, const unsigned* __restrict__ in1,
    const unsigned* __restrict__ wb, const float* __restrict__ bias,
    float bmult, void* __restrict__ outp) {
  constexpr int CHW = 2048;             // words per half-K weight chunk
  constexpr int WL = 2;                 // gload_lds per thread per chunk (256t)
  constexpr int H_U4 = 2112;            // uint4 per act half (4 rows x 66 x 8)
  constexpr int HJ = (H_U4 + 255) / 256;

  __shared__ unsigned Alds[8448];       // 4 rows x 66 x 32 words (one K-half)
  __shared__ unsigned Wlds[3][CHW];

  const int tid = threadIdx.x;
  const int lane = tid & 63;
  const int wav = tid >> 6;             // 0..3
  const int wr = wav >> 1;              // output row 0..1
  const int kh = wav & 1;               // K-quarter within current half
  const int l15 = lane & 15, q = lane >> 4;
  const int bid = blockIdx.x;
  const int n = bid & 7;                // same-n -> same XCD
  const int ochalf = (bid >> 3) & 1;
  const int hp = bid >> 4;              // 0..31
  const int h0 = hp * 2;

  const unsigned* wbase = wb + (size_t)ochalf * 18 * CHW;
  const size_t abase = ((size_t)n * 66 + h0) * (66 * 64);
  const uint4* g0 = (const uint4*)(in0 + abase);
  const uint4* g1 = (const uint4*)(in1 + abase);

  // ---- stage act K-half 0: pixel i>>3, sub i&7 -> global u4 pixel*16+sub ----
#pragma unroll
  for (int j = 0; j < HJ; ++j) {
    int i = tid + j * 256;
    if (i < H_U4) {
      int gi = ((i >> 3) << 4) + (i & 7);
      uint4 v = g0[gi];
      if (DUAL) v = addpk4(v, g1[gi]);
      *(uint4*)&Alds[4 * i] = v;
    }
  }
  // ---- weight chunks 0,1 async ----
#pragma unroll
  for (int s = 0; s < WL; ++s)
    gload16(wbase + s * 1024 + tid * 4, &Wlds[0][s * 1024 + wav * 256]);
#pragma unroll
  for (int s = 0; s < WL; ++s)
    gload16(wbase + CHW + s * 1024 + tid * 4, &Wlds[1][s * 1024 + wav * 256]);
  seal_lgkm_barrier();  // acts half0 sealed; weight loads stay in flight

  f32x4 acc[4][4];
#pragma unroll
  for (int m = 0; m < 4; ++m)
#pragma unroll
    for (int p = 0; p < 4; ++p) acc[m][p] = (f32x4)0.f;

  uint4 l0[HJ], l1[HJ];
  const int kq = kh * 16 + q * 4;       // word base within 32-word half

#pragma unroll
  for (int t = 0; t < 18; ++t) {
    if (t < 17) waitcnt_vm_lgkm<WL>();
    else waitcnt_vm_lgkm<0>();
    __builtin_amdgcn_s_barrier();
    __builtin_amdgcn_sched_barrier(0);

    // phase 9: swap act halves (all reads of half0 completed at barrier above)
    if (t == 9) {
#pragma unroll
      for (int j = 0; j < HJ; ++j) {
        int i = tid + j * 256;
        if (i < H_U4) {
          uint4 v = l0[j];
          if (DUAL) v = addpk4(v, l1[j]);
          *(uint4*)&Alds[4 * i] = v;
        }
      }
      seal_lgkm_barrier();
    }

    const unsigned* WB = Wlds[t % 3];
    const int tap = t % 9;
    const int dy = tap / 3, dx = tap % 3;
    const int arow = (wr + dy) * 66;

    __builtin_amdgcn_s_setprio(1);
    bf16x8 a[4];
#pragma unroll
    for (int m = 0; m < 4; ++m) {
      int r = m * 16 + l15;
      U4 u;
      u.u = *(const uint4*)&WB[r * 32 + (kq ^ ((r & 7) << 2))];
      a[m] = u.b;
    }
#pragma unroll
    for (int p = 0; p < 4; ++p) {
      int col = p * 16 + l15 + dx;
      U4 u;
      u.u = *(const uint4*)&Alds[(arow + col) * 32 + (kq ^ ((col & 7) << 2))];
      bf16x8 b = u.b;
#pragma unroll
      for (int m = 0; m < 4; ++m)
        acc[m][p] = __builtin_amdgcn_mfma_f32_16x16x32_bf16(a[m], b, acc[m][p], 0, 0, 0);
    }
    __builtin_amdgcn_s_setprio(0);
    __builtin_amdgcn_sched_barrier(0);

    // phase 8: issue act-half1 global loads (before chunk gloads -> older in q)
    if (t == 8) {
#pragma unroll
      for (int j = 0; j < HJ; ++j) {
        int i = tid + j * 256;
        if (i < H_U4) {
          int gi = ((i >> 3) << 4) + 8 + (i & 7);
          l0[j] = g0[gi];
          if (DUAL) l1[j] = g1[gi];
        }
      }
    }
    if (t + 2 < 18) {
#pragma unroll
      for (int s = 0; s < WL; ++s)
        gload16(wbase + (size_t)(t + 2) * CHW + s * 1024 + tid * 4,
                &Wlds[(t + 2) % 3][s * 1024 + wav * 256]);
    }
    __builtin_amdgcn_sched_barrier(0);
  }

  // ---- 2-way K reduction through LDS (acts dead) ----
  __syncthreads();
  float* R = (float*)Alds;
  if (kh) {
#pragma unroll
    for (int m = 0; m < 4; ++m)
#pragma unroll
      for (int p = 0; p < 4; ++p)
        *(f32x4*)&R[(wr * 16 + m * 4 + p) * 256 + lane * 4] = acc[m][p];
  }
  __syncthreads();
  if (kh) return;
#pragma unroll
  for (int m = 0; m < 4; ++m)
#pragma unroll
    for (int p = 0; p < 4; ++p)
      acc[m][p] += *(const f32x4*)&R[(wr * 16 + m * 4 + p) * 256 + lane * 4];

  // ---- epilogue (kh==0 waves; wave wr owns row h0+wr) ----
  const int obase = ochalf * 64;
  if (OUTF32) {
    float* out = (float*)outp;
#pragma unroll
    for (int m = 0; m < 4; ++m) {
      int oc0 = obase + m * 16 + q * 4;
      float4 bb = *(const float4*)&bias[oc0];
#pragma unroll
      for (int p = 0; p < 4; ++p) {
        int w = p * 16 + l15;
#pragma unroll
        for (int j = 0; j < 4; ++j)
          out[(((size_t)n * 128 + oc0 + j) * 64 + (h0 + wr)) * 64 + w] =
              acc[m][p][j] + ((const float*)&bb)[j] * bmult;
      }
    }
  } else {
    unsigned* out = (unsigned*)outp;
#pragma unroll
    for (int m = 0; m < 4; ++m) {
      int oc0 = obase + m * 16 + q * 4;
      float4 bb = *(const float4*)&bias[oc0];
      int icp0 = oc0 >> 1;
#pragma unroll
      for (int p = 0; p < 4; ++p) {
        int w = p * 16 + l15;
        int wp = w + 1;
        unsigned lo = pk_bf16(acc[m][p][0] + bb.x * bmult, acc[m][p][1] + bb.y * bmult);
        unsigned hi = pk_bf16(acc[m][p][2] + bb.z * bmult, acc[m][p][3] + bb.w * bmult);
        int pos = icp0 ^ ((wp & 7) << 2);
        size_t base = (((size_t)n * 66 + (h0 + 1 + wr)) * 66 + wp) * 64;
        *(uint2*)&out[base + pos] = make_uint2(lo, hi);
      }
    }
  }
}

// ---------------- launch ------------------------------------------------------
extern "C" void kernel_launch(void* const* d_in, const int* in_sizes, int n_in,
                              void* d_out, int out_size, void* d_ws,
                              size_t ws_size, hipStream_t stream) {
  const float* x = (const float*)d_in[0];
  const float* W0 = (const float*)d_in[1];
  const float* b0 = (const float*)d_in[2];
  const float* Wn = (const float*)d_in[3];
  const float* bn = (const float*)d_in[4];

  const size_t ACTB = (size_t)8 * 66 * 66 * 64;
  const size_t TW = (size_t)8 * 66 * 66 * 32;
  unsigned* B0 = (unsigned*)d_ws;
  unsigned* B1 = B0 + ACTB;
  unsigned* B2 = B1 + ACTB;
  unsigned* T = B2 + ACTB;
  unsigned* Wb = T + TW;

  setup_all<<<256, 512, 0, stream>>>(x, W0, Wn, B0, B1, B2, T, Wb);

  const unsigned* Wnode = Wb + 36864;
  const size_t NW = 73728;

  conv_stem<<<256, 512, 0, stream>>>(T, Wb, b0, B0);
  conv_node<false, false><<<512, 256, 0, stream>>>(B0, B0, Wnode, bn + 0, 1.f, B1);
  conv_node<true, false><<<512, 256, 0, stream>>>(B0, B1, Wnode + 1 * NW, bn + 128, 2.f, B2);
  conv_node<true, false><<<512, 256, 0, stream>>>(B1, B2, Wnode + 2 * NW, bn + 256, 2.f, B0);
  conv_node<true, false><<<512, 256, 0, stream>>>(B2, B0, Wnode + 3 * NW, bn + 384, 2.f, B1);
  conv_node<true, false><<<512, 256, 0, stream>>>(B0, B1, Wnode + 4 * NW, bn + 512, 2.f, B2);
  conv_node<true, true><<<512, 256, 0, stream>>>(B1, B2, Wnode + 5 * NW, bn + 640, 2.f, d_out);

  (void)in_sizes; (void)n_in; (void)out_size; (void)ws_size;
}